// Round 1
// baseline (521.807 us; speedup 1.0000x reference)
//
#include <hip/hip_runtime.h>
#include <cstdint>

typedef __bf16 bf16;
typedef bf16 bf16x8 __attribute__((ext_vector_type(8)));
typedef bf16 bf16x4 __attribute__((ext_vector_type(4)));
typedef float f32x4 __attribute__((ext_vector_type(4)));

#define MFMA16(a, b, c) __builtin_amdgcn_mfma_f32_16x16x32_bf16((a), (b), (c), 0, 0, 0)

#define GLOBAL_TO_LDS16(gptr, lptr)                                          \
  __builtin_amdgcn_global_load_lds(                                          \
      (const __attribute__((address_space(1))) void*)(gptr),                 \
      (__attribute__((address_space(3))) void*)(lptr), 16, 0, 0)

// problem dims
// H=16, D=1024, DK=DV=64, B=4, SQ=SK=1024, scale = sqrt(1024) = 32

// ---------------------------------------------------------------------------
// 1) flat fp32 -> bf16 convert for query/key/value/w_proj
// ---------------------------------------------------------------------------
__global__ __launch_bounds__(256) void cvt_all(
    const float* __restrict__ q, const float* __restrict__ k,
    const float* __restrict__ v, const float* __restrict__ wp,
    bf16* __restrict__ qb, bf16* __restrict__ kb,
    bf16* __restrict__ vb, bf16* __restrict__ wpb) {
  long i4 = ((long)blockIdx.x * 256 + threadIdx.x) * 4;  // element index
  const float* src;
  bf16* dst;
  long off;
  if (i4 < 4194304) {
    src = q; dst = qb; off = i4;
  } else if (i4 < 8388608) {
    src = k; dst = kb; off = i4 - 4194304;
  } else if (i4 < 12582912) {
    src = v; dst = vb; off = i4 - 8388608;
  } else {
    src = wp; dst = wpb; off = i4 - 12582912;
  }
  float4 f = *(const float4*)(src + off);
  bf16x4 o;
  o[0] = (bf16)f.x; o[1] = (bf16)f.y; o[2] = (bf16)f.z; o[3] = (bf16)f.w;
  *(bf16x4*)(dst + off) = o;
}

// ---------------------------------------------------------------------------
// 2) w_{q,k,v}[h][d][kk] fp32 -> wT[h*64+kk][d] bf16  (BT layout for GEMM)
// ---------------------------------------------------------------------------
__global__ __launch_bounds__(256) void wtrans(
    const float* __restrict__ wq, const float* __restrict__ wk,
    const float* __restrict__ wv, bf16* __restrict__ wqT,
    bf16* __restrict__ wkT, bf16* __restrict__ wvT) {
  int z = blockIdx.z;
  const float* src = (z == 0) ? wq : ((z == 1) ? wk : wv);
  bf16* dst = (z == 0) ? wqT : ((z == 1) ? wkT : wvT);
  int t = blockIdx.x * 256 + threadIdx.x;  // 0 .. 1048575
  int d = t & 1023;
  int r = t >> 10;        // h*64 + kk
  int h = r >> 6, kk = r & 63;
  dst[t] = (bf16)src[(h << 16) + (d << 6) + kk];
}

// ---------------------------------------------------------------------------
// shared GEMM mainloop: C[128x128] += A[128xK] * BT[128xK]^T, K = 1024
// 256 threads = 4 waves in 2x2; each wave 64x64 via 4x4 tiles of 16x16x32
// ---------------------------------------------------------------------------
__device__ __forceinline__ void gemm_mainloop(
    const bf16* __restrict__ A, const bf16* __restrict__ BT, bf16* As,
    bf16* Bs, int m0, int n0, f32x4 acc[4][4]) {
  const int tid = threadIdx.x;
  const int lane = tid & 63, wave = tid >> 6;
  const int wm = wave >> 1, wn = wave & 1;
  const int ln = lane & 15, ko8 = (lane >> 4) * 8;
  const int c0 = tid, c1 = 256 + tid;
  const int r0 = c0 >> 2, q0 = c0 & 3;
  const int r1 = c1 >> 2, q1 = c1 & 3;

  for (int k0 = 0; k0 < 1024; k0 += 32) {
    GLOBAL_TO_LDS16(A + (long)(m0 + r0) * 1024 + k0 + q0 * 8, As + c0 * 8);
    GLOBAL_TO_LDS16(A + (long)(m0 + r1) * 1024 + k0 + q1 * 8, As + c1 * 8);
    GLOBAL_TO_LDS16(BT + (long)(n0 + r0) * 1024 + k0 + q0 * 8, Bs + c0 * 8);
    GLOBAL_TO_LDS16(BT + (long)(n0 + r1) * 1024 + k0 + q1 * 8, Bs + c1 * 8);
    __syncthreads();
    bf16x8 af[4], bg[4];
#pragma unroll
    for (int t = 0; t < 4; ++t) {
      af[t] = *(const bf16x8*)(As + (wm * 64 + t * 16 + ln) * 32 + ko8);
      bg[t] = *(const bf16x8*)(Bs + (wn * 64 + t * 16 + ln) * 32 + ko8);
    }
#pragma unroll
    for (int i = 0; i < 4; ++i)
#pragma unroll
      for (int j = 0; j < 4; ++j) acc[i][j] = MFMA16(af[i], bg[j], acc[i][j]);
    __syncthreads();
  }
}

// ---------------------------------------------------------------------------
// 3) QKV projections.  z=0: Q (alpha=1/32, layout [b,h,s,dk])
//                      z=1: K (layout [b,h,s,dk])   z=2: V -> Vt[b,h,dv,s]
// ---------------------------------------------------------------------------
__global__ __launch_bounds__(256) void qkv_gemm(
    const bf16* __restrict__ qb, const bf16* __restrict__ kb,
    const bf16* __restrict__ vb, const bf16* __restrict__ wqT,
    const bf16* __restrict__ wkT, const bf16* __restrict__ wvT,
    bf16* __restrict__ Qd, bf16* __restrict__ Kd, bf16* __restrict__ Vtd) {
  __shared__ bf16 As[128 * 32];
  __shared__ bf16 Bs[128 * 32];
  int z = blockIdx.z;
  const bf16* A = (z == 0) ? qb : ((z == 1) ? kb : vb);
  const bf16* BT = (z == 0) ? wqT : ((z == 1) ? wkT : wvT);
  int m0 = blockIdx.x * 128, n0 = blockIdx.y * 128;
  f32x4 acc[4][4] = {};
  gemm_mainloop(A, BT, As, Bs, m0, n0, acc);

  const int tid = threadIdx.x, lane = tid & 63, wave = tid >> 6;
  const int wm = wave >> 1, wn = wave & 1, ln = lane & 15, lk = lane >> 4;
  const float alpha = (z == 0) ? 0.03125f : 1.0f;  // fold softmax 1/sqrt(D)
  bf16* dstQK = (z == 0) ? Qd : Kd;
#pragma unroll
  for (int ti = 0; ti < 4; ++ti)
#pragma unroll
    for (int tj = 0; tj < 4; ++tj) {
      int n = n0 + wn * 64 + tj * 16 + ln;
#pragma unroll
      for (int i = 0; i < 4; ++i) {
        int m = m0 + wm * 64 + ti * 16 + lk * 4 + i;
        float vv = acc[ti][tj][i] * alpha;
        if (z <= 1) {
          // Q/K: ((b*16 + h)*1024 + s)*64 + dk
          long addr =
              ((((long)(m >> 10) * 16 + (n >> 6)) << 10) + (m & 1023)) * 64 +
              (n & 63);
          dstQK[addr] = (bf16)vv;
        } else {
          // Vt: ((b*16 + h)*64 + dv)*1024 + s
          long addr =
              ((((long)(m >> 10) * 16 + (n >> 6)) << 6) + (n & 63)) * 1024 +
              (m & 1023);
          Vtd[addr] = (bf16)vv;
        }
      }
    }
}

// ---------------------------------------------------------------------------
// 4) fused attention: scores (regs) -> exact softmax -> attn fp32 out + PV
//    block = (b, h, 16 q-rows), 4 waves; wave w owns sk strip [w*256, w*256+256)
// ---------------------------------------------------------------------------
__global__ __launch_bounds__(256) void attn_kernel(
    const bf16* __restrict__ Qd, const bf16* __restrict__ Kd,
    const bf16* __restrict__ Vtd, float* __restrict__ attns,
    bf16* __restrict__ Ob) {
  __shared__ bf16 P[16 * 1024];          // xor-swizzled P (A-layout source)
  __shared__ float wstats[4][16][2];     // per-wave (max, sumexp) per row

  int qt = blockIdx.x, h = blockIdx.y, b = blockIdx.z;
  int q0 = qt * 16;
  int tid = threadIdx.x, lane = tid & 63, wave = tid >> 6;
  int ln = lane & 15, lk = lane >> 4;

  const bf16* Qbh = Qd + (((long)(b * 16 + h)) << 10) * 64;
  const bf16* Kbh = Kd + (((long)(b * 16 + h)) << 10) * 64;
  const bf16* Vbh = Vtd + (((long)(b * 16 + h)) << 6) * 1024;

  // Q A-fragments (2 k-steps of 32 over DK=64)
  bf16x8 aq0 = *(const bf16x8*)(Qbh + (long)(q0 + ln) * 64 + lk * 8);
  bf16x8 aq1 = *(const bf16x8*)(Qbh + (long)(q0 + ln) * 64 + 32 + lk * 8);

  // scores for this wave's 16x256 strip, held in registers
  f32x4 sacc[16];
#pragma unroll
  for (int t = 0; t < 16; ++t) {
    int sk0 = wave * 256 + t * 16;
    f32x4 a = {0.f, 0.f, 0.f, 0.f};
    bf16x8 bk0 = *(const bf16x8*)(Kbh + (long)(sk0 + ln) * 64 + lk * 8);
    bf16x8 bk1 = *(const bf16x8*)(Kbh + (long)(sk0 + ln) * 64 + 32 + lk * 8);
    a = MFMA16(aq0, bk0, a);
    a = MFMA16(aq1, bk1, a);
    sacc[t] = a;
  }

  // wave-local softmax stats per row (row = lk*4 + i), cols across t and ln
  float mw[4], lw[4];
#pragma unroll
  for (int i = 0; i < 4; ++i) {
    float m = sacc[0][i];
#pragma unroll
    for (int t = 1; t < 16; ++t) m = fmaxf(m, sacc[t][i]);
#pragma unroll
    for (int off = 1; off < 16; off <<= 1) m = fmaxf(m, __shfl_xor(m, off, 64));
    mw[i] = m;
  }
#pragma unroll
  for (int i = 0; i < 4; ++i) {
    float s = 0.f;
#pragma unroll
    for (int t = 0; t < 16; ++t) {
      float e = __expf(sacc[t][i] - mw[i]);
      sacc[t][i] = e;  // keep e = exp(s - mw) in regs
      s += e;
    }
#pragma unroll
    for (int off = 1; off < 16; off <<= 1) s += __shfl_xor(s, off, 64);
    lw[i] = s;
  }
  if (ln == 0) {
#pragma unroll
    for (int i = 0; i < 4; ++i) {
      wstats[wave][lk * 4 + i][0] = mw[i];
      wstats[wave][lk * 4 + i][1] = lw[i];
    }
  }
  __syncthreads();

  // combine across waves -> attn = sacc * fscale,  fscale = exp(mw - M)/L
  float fscale[4];
#pragma unroll
  for (int i = 0; i < 4; ++i) {
    int r = lk * 4 + i;
    float M = fmaxf(fmaxf(wstats[0][r][0], wstats[1][r][0]),
                    fmaxf(wstats[2][r][0], wstats[3][r][0]));
    float L = 0.f;
#pragma unroll
    for (int w = 0; w < 4; ++w)
      L += wstats[w][r][1] * __expf(wstats[w][r][0] - M);
    fscale[i] = __expf(mw[i] - M) / L;
  }

  // write attn fp32 (coalesced from regs) + P bf16 into swizzled LDS
  float* arow_base = attns + ((((long)(h * 4 + b)) << 10) + q0) * 1024;
#pragma unroll
  for (int t = 0; t < 16; ++t) {
    int col = wave * 256 + t * 16 + ln;
    int g = col >> 3, cw = col & 7;
#pragma unroll
    for (int i = 0; i < 4; ++i) {
      int r = lk * 4 + i;
      float a = sacc[t][i] * fscale[i];
      arow_base[(long)r * 1024 + col] = a;
      P[(r << 10) + ((g ^ (r & 7)) << 3) + cw] = (bf16)a;
    }
  }
  __syncthreads();

  // PV: wave w computes O[16 x 16] for dv in [w*16, w*16+16)
  f32x4 oacc = {0.f, 0.f, 0.f, 0.f};
#pragma unroll 4
  for (int s0 = 0; s0 < 1024; s0 += 32) {
    int g = (s0 >> 3) + lk;
    bf16x8 ap = *(const bf16x8*)(P + (ln << 10) + ((g ^ (ln & 7)) << 3));
    bf16x8 bv =
        *(const bf16x8*)(Vbh + (long)(wave * 16 + ln) * 1024 + s0 + lk * 8);
    oacc = MFMA16(ap, bv, oacc);
  }
#pragma unroll
  for (int i = 0; i < 4; ++i) {
    int qrow = q0 + lk * 4 + i;
    Ob[((((long)b) << 10) + qrow) * 1024 + (h << 6) + wave * 16 + ln] =
        (bf16)oacc[i];
  }
}

// ---------------------------------------------------------------------------
// 5) out = O @ w_proj^T + b_proj  (fp32 out)
// ---------------------------------------------------------------------------
__global__ __launch_bounds__(256) void out_gemm(
    const bf16* __restrict__ Ob, const bf16* __restrict__ wpb,
    const float* __restrict__ bias, float* __restrict__ out) {
  __shared__ bf16 As[128 * 32];
  __shared__ bf16 Bs[128 * 32];
  int m0 = blockIdx.x * 128, n0 = blockIdx.y * 128;
  f32x4 acc[4][4] = {};
  gemm_mainloop(Ob, wpb, As, Bs, m0, n0, acc);

  const int tid = threadIdx.x, lane = tid & 63, wave = tid >> 6;
  const int wm = wave >> 1, wn = wave & 1, ln = lane & 15, lk = lane >> 4;
#pragma unroll
  for (int ti = 0; ti < 4; ++ti)
#pragma unroll
    for (int tj = 0; tj < 4; ++tj) {
      int n = n0 + wn * 64 + tj * 16 + ln;
      float bn = bias[n];
#pragma unroll
      for (int i = 0; i < 4; ++i) {
        int m = m0 + wm * 64 + ti * 16 + lk * 4 + i;
        out[(long)m * 1024 + n] = acc[ti][tj][i] + bn;
      }
    }
}

// ---------------------------------------------------------------------------
extern "C" void kernel_launch(void* const* d_in, const int* in_sizes, int n_in,
                              void* d_out, int out_size, void* d_ws,
                              size_t ws_size, hipStream_t stream) {
  const float* query = (const float*)d_in[0];
  const float* key = (const float*)d_in[1];
  const float* value = (const float*)d_in[2];
  const float* w_q = (const float*)d_in[3];
  const float* w_k = (const float*)d_in[4];
  const float* w_v = (const float*)d_in[5];
  const float* w_proj = (const float*)d_in[6];
  const float* b_proj = (const float*)d_in[7];

  char* ws = (char*)d_ws;
  bf16* qb = (bf16*)(ws);                       // 8 MB  [4096,1024]
  bf16* kb = (bf16*)(ws + (8ul << 20));         // 8 MB
  bf16* vb = (bf16*)(ws + (16ul << 20));        // 8 MB
  bf16* wqT = (bf16*)(ws + (24ul << 20));       // 2 MB  [1024,1024] BT
  bf16* wkT = (bf16*)(ws + (26ul << 20));       // 2 MB
  bf16* wvT = (bf16*)(ws + (28ul << 20));       // 2 MB
  bf16* wpb = (bf16*)(ws + (30ul << 20));       // 2 MB  w_proj BT layout
  bf16* Qd = (bf16*)(ws + (32ul << 20));        // 8 MB  [b,h,s,dk]
  bf16* Kd = (bf16*)(ws + (40ul << 20));        // 8 MB  [b,h,s,dk]
  bf16* Vtd = (bf16*)(ws + (48ul << 20));       // 8 MB  [b,h,dv,s]
  bf16* Ob = (bf16*)(ws + (56ul << 20));        // 8 MB  [b*sq, h*dv]
  // total 64 MB of d_ws

  float* out = (float*)d_out;                   // [4096, 1024] fp32
  float* attns = out + 4194304;                 // [64, 1024, 1024] fp32

  cvt_all<<<13312, 256, 0, stream>>>(query, key, value, w_proj, qb, kb, vb,
                                     wpb);
  wtrans<<<dim3(4096, 1, 3), 256, 0, stream>>>(w_q, w_k, w_v, wqT, wkT, wvT);
  qkv_gemm<<<dim3(32, 8, 3), 256, 0, stream>>>(qb, kb, vb, wqT, wkT, wvT, Qd,
                                               Kd, Vtd);
  attn_kernel<<<dim3(64, 16, 4), 256, 0, stream>>>(Qd, Kd, Vtd, attns, Ob);
  out_gemm<<<dim3(32, 8), 256, 0, stream>>>(Ob, wpb, b_proj, out);
}

// Round 2
// 500.051 us; speedup vs baseline: 1.0435x; 1.0435x over previous
//
#include <hip/hip_runtime.h>
#include <cstdint>

typedef __bf16 bf16;
typedef bf16 bf16x8 __attribute__((ext_vector_type(8)));
typedef bf16 bf16x4 __attribute__((ext_vector_type(4)));
typedef float f32x4 __attribute__((ext_vector_type(4)));

#define MFMA16(a, b, c) __builtin_amdgcn_mfma_f32_16x16x32_bf16((a), (b), (c), 0, 0, 0)

#define GLOBAL_TO_LDS16(gptr, lptr)                                          \
  __builtin_amdgcn_global_load_lds(                                          \
      (const __attribute__((address_space(1))) void*)(gptr),                 \
      (__attribute__((address_space(3))) void*)(lptr), 16, 0, 0)

// problem dims: H=16, D=1024, DK=DV=64, B=4, SQ=SK=1024, scale = 32

// ---------------------------------------------------------------------------
// 1) flat fp32 -> bf16 convert for query/key/value/w_proj
// ---------------------------------------------------------------------------
__global__ __launch_bounds__(256) void cvt_all(
    const float* __restrict__ q, const float* __restrict__ k,
    const float* __restrict__ v, const float* __restrict__ wp,
    bf16* __restrict__ qb, bf16* __restrict__ kb,
    bf16* __restrict__ vb, bf16* __restrict__ wpb) {
  long i4 = ((long)blockIdx.x * 256 + threadIdx.x) * 4;
  const float* src;
  bf16* dst;
  long off;
  if (i4 < 4194304) {
    src = q; dst = qb; off = i4;
  } else if (i4 < 8388608) {
    src = k; dst = kb; off = i4 - 4194304;
  } else if (i4 < 12582912) {
    src = v; dst = vb; off = i4 - 8388608;
  } else {
    src = wp; dst = wpb; off = i4 - 12582912;
  }
  float4 f = *(const float4*)(src + off);
  bf16x4 o;
  o[0] = (bf16)f.x; o[1] = (bf16)f.y; o[2] = (bf16)f.z; o[3] = (bf16)f.w;
  *(bf16x4*)(dst + off) = o;
}

// ---------------------------------------------------------------------------
// 2) LDS-tiled transpose: w_{q,k,v}[h][d][kk] fp32 -> wT[h*64+kk][d] bf16
//    grid (16 d-tiles, 16 h, 3 matrices), block 256
// ---------------------------------------------------------------------------
__global__ __launch_bounds__(256) void wtrans(
    const float* __restrict__ wq, const float* __restrict__ wk,
    const float* __restrict__ wv, bf16* __restrict__ wqT,
    bf16* __restrict__ wkT, bf16* __restrict__ wvT) {
  __shared__ bf16 tile[64][72];  // 72: 144 B row stride, conflict-free gather
  int dt = blockIdx.x, h = blockIdx.y, z = blockIdx.z;
  const float* src =
      ((z == 0) ? wq : (z == 1) ? wk : wv) + (long)h * 65536 + dt * 64 * 64;
  bf16* dstM = (z == 0) ? wqT : (z == 1) ? wkT : wvT;
  int t = threadIdx.x;
#pragma unroll
  for (int i = 0; i < 4; ++i) {
    int chunk = t + i * 256;           // 1024 chunks of 4 floats
    int r = chunk >> 4, c4 = chunk & 15;
    float4 f = *(const float4*)(src + r * 64 + c4 * 4);
    bf16x4 o;
    o[0] = (bf16)f.x; o[1] = (bf16)f.y; o[2] = (bf16)f.z; o[3] = (bf16)f.w;
    *(bf16x4*)&tile[r][c4 * 4] = o;
  }
  __syncthreads();
  int kk = t & 63, sc = t >> 6;        // gather 16 d's for this kk
  bf16 tmp[16];
#pragma unroll
  for (int j = 0; j < 16; ++j) tmp[j] = tile[sc * 16 + j][kk];
  bf16* dst = dstM + ((long)h * 64 + kk) * 1024 + dt * 64 + sc * 16;
  *(bf16x8*)dst = *(bf16x8*)tmp;
  *(bf16x8*)(dst + 8) = *(bf16x8*)(tmp + 8);
}

// ---------------------------------------------------------------------------
// 2b) LDS-tiled transpose: Vd[b,h,s,dv] bf16 -> Vt[b,h,dv,s] bf16
//     grid (16 s-tiles, 64 bh), block 256
// ---------------------------------------------------------------------------
__global__ __launch_bounds__(256) void vtrans(const bf16* __restrict__ Vd,
                                              bf16* __restrict__ Vt) {
  __shared__ bf16 tile[64][72];
  int st = blockIdx.x, bh = blockIdx.y;
  const bf16* src = Vd + ((long)bh * 1024 + st * 64) * 64;
  int t = threadIdx.x;
#pragma unroll
  for (int i = 0; i < 2; ++i) {
    int chunk = t + i * 256;           // 512 chunks of 8 bf16
    int r = chunk >> 3, c8 = chunk & 7;
    *(bf16x8*)&tile[r][c8 * 8] = *(const bf16x8*)(src + r * 64 + c8 * 8);
  }
  __syncthreads();
  int d = t & 63, sc = t >> 6;
  bf16 tmp[16];
#pragma unroll
  for (int j = 0; j < 16; ++j) tmp[j] = tile[sc * 16 + j][d];
  bf16* dst = Vt + ((long)bh * 64 + d) * 1024 + st * 64 + sc * 16;
  *(bf16x8*)dst = *(bf16x8*)tmp;
  *(bf16x8*)(dst + 8) = *(bf16x8*)(tmp + 8);
}

// ---------------------------------------------------------------------------
// shared GEMM mainloop: C[128x128] += A[128xK] * BT[128xK]^T, K = 1024
// ---------------------------------------------------------------------------
__device__ __forceinline__ void gemm_mainloop(
    const bf16* __restrict__ A, const bf16* __restrict__ BT, bf16* As,
    bf16* Bs, int m0, int n0, f32x4 acc[4][4]) {
  const int tid = threadIdx.x;
  const int lane = tid & 63, wave = tid >> 6;
  const int wm = wave >> 1, wn = wave & 1;
  const int ln = lane & 15, ko8 = (lane >> 4) * 8;
  const int c0 = tid, c1 = 256 + tid;
  const int r0 = c0 >> 2, q0 = c0 & 3;
  const int r1 = c1 >> 2, q1 = c1 & 3;

  for (int k0 = 0; k0 < 1024; k0 += 32) {
    GLOBAL_TO_LDS16(A + (long)(m0 + r0) * 1024 + k0 + q0 * 8, As + c0 * 8);
    GLOBAL_TO_LDS16(A + (long)(m0 + r1) * 1024 + k0 + q1 * 8, As + c1 * 8);
    GLOBAL_TO_LDS16(BT + (long)(n0 + r0) * 1024 + k0 + q0 * 8, Bs + c0 * 8);
    GLOBAL_TO_LDS16(BT + (long)(n0 + r1) * 1024 + k0 + q1 * 8, Bs + c1 * 8);
    __syncthreads();
    bf16x8 af[4], bg[4];
#pragma unroll
    for (int t = 0; t < 4; ++t) {
      af[t] = *(const bf16x8*)(As + (wm * 64 + t * 16 + ln) * 32 + ko8);
      bg[t] = *(const bf16x8*)(Bs + (wn * 64 + t * 16 + ln) * 32 + ko8);
    }
#pragma unroll
    for (int i = 0; i < 4; ++i)
#pragma unroll
      for (int j = 0; j < 4; ++j) acc[i][j] = MFMA16(af[i], bg[j], acc[i][j]);
    __syncthreads();
  }
}

// ---------------------------------------------------------------------------
// 3) QKV projections -> [b,h,s,dk] for all three (coalesced epilogue).
//    z=0: Q (alpha = 1/32)  z=1: K  z=2: V (transposed later by vtrans)
// ---------------------------------------------------------------------------
__global__ __launch_bounds__(256) void qkv_gemm(
    const bf16* __restrict__ qb, const bf16* __restrict__ kb,
    const bf16* __restrict__ vb, const bf16* __restrict__ wqT,
    const bf16* __restrict__ wkT, const bf16* __restrict__ wvT,
    bf16* __restrict__ Qd, bf16* __restrict__ Kd, bf16* __restrict__ Vd) {
  __shared__ bf16 As[128 * 32];
  __shared__ bf16 Bs[128 * 32];
  int z = blockIdx.z;
  const bf16* A = (z == 0) ? qb : ((z == 1) ? kb : vb);
  const bf16* BT = (z == 0) ? wqT : ((z == 1) ? wkT : wvT);
  int m0 = blockIdx.x * 128, n0 = blockIdx.y * 128;
  f32x4 acc[4][4] = {};
  gemm_mainloop(A, BT, As, Bs, m0, n0, acc);

  const int tid = threadIdx.x, lane = tid & 63, wave = tid >> 6;
  const int wm = wave >> 1, wn = wave & 1, ln = lane & 15, lk = lane >> 4;
  const float alpha = (z == 0) ? 0.03125f : 1.0f;
  bf16* dst = (z == 0) ? Qd : ((z == 1) ? Kd : Vd);
#pragma unroll
  for (int ti = 0; ti < 4; ++ti)
#pragma unroll
    for (int tj = 0; tj < 4; ++tj) {
      int n = n0 + wn * 64 + tj * 16 + ln;
#pragma unroll
      for (int i = 0; i < 4; ++i) {
        int m = m0 + wm * 64 + ti * 16 + lk * 4 + i;
        // [b,h,s,dk]: ((b*16+h)*1024 + s)*64 + dk
        long addr =
            ((((long)(m >> 10) * 16 + (n >> 6)) << 10) + (m & 1023)) * 64 +
            (n & 63);
        dst[addr] = (bf16)(acc[ti][tj][i] * alpha);
      }
    }
}

// ---------------------------------------------------------------------------
// 4) fused attention: scores (regs) -> exact softmax -> attn fp32 out + PV
// ---------------------------------------------------------------------------
__global__ __launch_bounds__(256, 2) void attn_kernel(
    const bf16* __restrict__ Qd, const bf16* __restrict__ Kd,
    const bf16* __restrict__ Vtd, float* __restrict__ attns,
    bf16* __restrict__ Ob) {
  __shared__ bf16 P[16 * 1024];
  __shared__ float wstats[4][16][2];

  int qt = blockIdx.x, h = blockIdx.y, b = blockIdx.z;
  int q0 = qt * 16;
  int tid = threadIdx.x, lane = tid & 63, wave = tid >> 6;
  int ln = lane & 15, lk = lane >> 4;

  const bf16* Qbh = Qd + (((long)(b * 16 + h)) << 10) * 64;
  const bf16* Kbh = Kd + (((long)(b * 16 + h)) << 10) * 64;
  const bf16* Vbh = Vtd + (((long)(b * 16 + h)) << 6) * 1024;

  bf16x8 aq0 = *(const bf16x8*)(Qbh + (long)(q0 + ln) * 64 + lk * 8);
  bf16x8 aq1 = *(const bf16x8*)(Qbh + (long)(q0 + ln) * 64 + 32 + lk * 8);

  f32x4 sacc[16];
#pragma unroll
  for (int t = 0; t < 16; ++t) {
    int sk0 = wave * 256 + t * 16;
    f32x4 a = {0.f, 0.f, 0.f, 0.f};
    bf16x8 bk0 = *(const bf16x8*)(Kbh + (long)(sk0 + ln) * 64 + lk * 8);
    bf16x8 bk1 = *(const bf16x8*)(Kbh + (long)(sk0 + ln) * 64 + 32 + lk * 8);
    a = MFMA16(aq0, bk0, a);
    a = MFMA16(aq1, bk1, a);
    sacc[t] = a;
  }

  float mw[4], lw[4];
#pragma unroll
  for (int i = 0; i < 4; ++i) {
    float m = sacc[0][i];
#pragma unroll
    for (int t = 1; t < 16; ++t) m = fmaxf(m, sacc[t][i]);
#pragma unroll
    for (int off = 1; off < 16; off <<= 1) m = fmaxf(m, __shfl_xor(m, off, 64));
    mw[i] = m;
  }
#pragma unroll
  for (int i = 0; i < 4; ++i) {
    float s = 0.f;
#pragma unroll
    for (int t = 0; t < 16; ++t) {
      float e = __expf(sacc[t][i] - mw[i]);
      sacc[t][i] = e;
      s += e;
    }
#pragma unroll
    for (int off = 1; off < 16; off <<= 1) s += __shfl_xor(s, off, 64);
    lw[i] = s;
  }
  if (ln == 0) {
#pragma unroll
    for (int i = 0; i < 4; ++i) {
      wstats[wave][lk * 4 + i][0] = mw[i];
      wstats[wave][lk * 4 + i][1] = lw[i];
    }
  }
  __syncthreads();

  float fscale[4];
#pragma unroll
  for (int i = 0; i < 4; ++i) {
    int r = lk * 4 + i;
    float M = fmaxf(fmaxf(wstats[0][r][0], wstats[1][r][0]),
                    fmaxf(wstats[2][r][0], wstats[3][r][0]));
    float L = 0.f;
#pragma unroll
    for (int w = 0; w < 4; ++w)
      L += wstats[w][r][1] * __expf(wstats[w][r][0] - M);
    fscale[i] = __expf(mw[i] - M) / L;
  }

  float* arow_base = attns + ((((long)(h * 4 + b)) << 10) + q0) * 1024;
#pragma unroll
  for (int t = 0; t < 16; ++t) {
    int col = wave * 256 + t * 16 + ln;
    int g = col >> 3, cw = col & 7;
#pragma unroll
    for (int i = 0; i < 4; ++i) {
      int r = lk * 4 + i;
      float a = sacc[t][i] * fscale[i];
      arow_base[(long)r * 1024 + col] = a;
      P[(r << 10) + ((g ^ (r & 7)) << 3) + cw] = (bf16)a;
    }
  }
  __syncthreads();

  f32x4 oacc = {0.f, 0.f, 0.f, 0.f};
#pragma unroll 4
  for (int s0 = 0; s0 < 1024; s0 += 32) {
    int g = (s0 >> 3) + lk;
    bf16x8 ap = *(const bf16x8*)(P + (ln << 10) + ((g ^ (ln & 7)) << 3));
    bf16x8 bv =
        *(const bf16x8*)(Vbh + (long)(wave * 16 + ln) * 1024 + s0 + lk * 8);
    oacc = MFMA16(ap, bv, oacc);
  }
#pragma unroll
  for (int i = 0; i < 4; ++i) {
    int qrow = q0 + lk * 4 + i;
    Ob[((((long)b) << 10) + qrow) * 1024 + (h << 6) + wave * 16 + ln] =
        (bf16)oacc[i];
  }
}

// ---------------------------------------------------------------------------
// 5) out = O @ w_proj^T + b_proj  (fp32 out)
// ---------------------------------------------------------------------------
__global__ __launch_bounds__(256) void out_gemm(
    const bf16* __restrict__ Ob, const bf16* __restrict__ wpb,
    const float* __restrict__ bias, float* __restrict__ out) {
  __shared__ bf16 As[128 * 32];
  __shared__ bf16 Bs[128 * 32];
  int m0 = blockIdx.x * 128, n0 = blockIdx.y * 128;
  f32x4 acc[4][4] = {};
  gemm_mainloop(Ob, wpb, As, Bs, m0, n0, acc);

  const int tid = threadIdx.x, lane = tid & 63, wave = tid >> 6;
  const int wm = wave >> 1, wn = wave & 1, ln = lane & 15, lk = lane >> 4;
#pragma unroll
  for (int ti = 0; ti < 4; ++ti)
#pragma unroll
    for (int tj = 0; tj < 4; ++tj) {
      int n = n0 + wn * 64 + tj * 16 + ln;
      float bn = bias[n];
#pragma unroll
      for (int i = 0; i < 4; ++i) {
        int m = m0 + wm * 64 + ti * 16 + lk * 4 + i;
        out[(long)m * 1024 + n] = acc[ti][tj][i] + bn;
      }
    }
}

// ---------------------------------------------------------------------------
extern "C" void kernel_launch(void* const* d_in, const int* in_sizes, int n_in,
                              void* d_out, int out_size, void* d_ws,
                              size_t ws_size, hipStream_t stream) {
  const float* query = (const float*)d_in[0];
  const float* key = (const float*)d_in[1];
  const float* value = (const float*)d_in[2];
  const float* w_q = (const float*)d_in[3];
  const float* w_k = (const float*)d_in[4];
  const float* w_v = (const float*)d_in[5];
  const float* w_proj = (const float*)d_in[6];
  const float* b_proj = (const float*)d_in[7];

  char* ws = (char*)d_ws;
  bf16* qb = (bf16*)(ws);                  // 8 MB  [4096,1024]
  bf16* kb = (bf16*)(ws + (8ul << 20));    // 8 MB
  bf16* vb = (bf16*)(ws + (16ul << 20));   // 8 MB
  bf16* wqT = (bf16*)(ws + (24ul << 20));  // 2 MB  [1024,1024] BT
  bf16* wkT = (bf16*)(ws + (26ul << 20));  // 2 MB
  bf16* wvT = (bf16*)(ws + (28ul << 20));  // 2 MB
  bf16* wpb = (bf16*)(ws + (30ul << 20));  // 2 MB  w_proj BT layout
  bf16* Qd = (bf16*)(ws + (32ul << 20));   // 8 MB  [b,h,s,dk]
  bf16* Kd = (bf16*)(ws + (40ul << 20));   // 8 MB  [b,h,s,dk]
  bf16* Vtd = (bf16*)(ws + (48ul << 20));  // 8 MB  [b,h,dv,s]
  bf16* Ob = (bf16*)(ws + (56ul << 20));   // 8 MB  [b*sq, h*dv]
  bf16* Vd = (bf16*)(ws + (64ul << 20));   // 8 MB  [b,h,s,dv]
  // total 72 MB of d_ws

  float* out = (float*)d_out;              // [4096, 1024] fp32
  float* attns = out + 4194304;            // [64, 1024, 1024] fp32

  cvt_all<<<13312, 256, 0, stream>>>(query, key, value, w_proj, qb, kb, vb,
                                     wpb);
  wtrans<<<dim3(16, 16, 3), 256, 0, stream>>>(w_q, w_k, w_v, wqT, wkT, wvT);
  qkv_gemm<<<dim3(32, 8, 3), 256, 0, stream>>>(qb, kb, vb, wqT, wkT, wvT, Qd,
                                               Kd, Vd);
  vtrans<<<dim3(16, 64), 256, 0, stream>>>(Vd, Vtd);
  attn_kernel<<<dim3(64, 16, 4), 256, 0, stream>>>(Qd, Kd, Vtd, attns, Ob);
  out_gemm<<<dim3(32, 8), 256, 0, stream>>>(Ob, wpb, b_proj, out);
}